// Round 6
// baseline (317.038 us; speedup 1.0000x reference)
//
#include <hip/hip_runtime.h>
#include <stdint.h>

#define BB 8192
#define NN 50

typedef _Float16 half8 __attribute__((ext_vector_type(8)));
typedef float floatx4 __attribute__((ext_vector_type(4)));

union FragU { uint4 u; half8 h; };
static __device__ __forceinline__ half8 u2h(uint4 u) { FragU f; f.u = u; return f.h; }

static __device__ __forceinline__ uint32_t pk2u(float a, float b) {
    auto p = __builtin_amdgcn_cvt_pkrtz(a, b);
    uint32_t u; __builtin_memcpy(&u, &p, 4); return u;
}

#define MFMA(A, B, C) __builtin_amdgcn_mfma_f32_16x16x32_f16((A), (B), (C), 0, 0, 0)

static __device__ __forceinline__ float frcp(float x) {
#if __has_builtin(__builtin_amdgcn_rcpf)
    return __builtin_amdgcn_rcpf(x);
#else
    return 1.0f / x;
#endif
}
static __device__ __forceinline__ float fexp2(float x) {
#if __has_builtin(__builtin_amdgcn_exp2f)
    return __builtin_amdgcn_exp2f(x);
#else
    return __expf(0.69314718056f * x);
#endif
}

// Raw barrier: drain LDS ops only (vmem prefetches stay in flight).
static __device__ __forceinline__ void bar_lds() {
    asm volatile("s_waitcnt lgkmcnt(0)" ::: "memory");
    __builtin_amdgcn_s_barrier();
}

// Producer/consumer wave specialization. Block = 4 waves, 16 items.
// Roles (rotated per block for SIMD mixing): 2 consumers (recurrence: whh GEMM +
// gate math, rows [32c,32c+32)), 2 producers (x-build + gi = scaledWih@x + gathers,
// feeding consumer c=p through double-buffered gi C-frag LDS, 1 raw barrier/step).
// x transpose is wave-private LDS (no barrier; R0-proven). gi(t) is h-independent
// so producers run exactly 1 step ahead. Barrier counts identical across roles.
// launch_bounds(256,3): gentle VGPR cap 170 (R2 lesson: never force below need).
__global__ __launch_bounds__(256, 3)
void dygkt8(const float* __restrict__ nodef, const float* __restrict__ edgef,
            const int* __restrict__ src_ids, const int* __restrict__ dst_ids,
            const float* __restrict__ times,
            const int* __restrict__ s_nids, const int* __restrict__ s_eids,
            const float* __restrict__ s_ts,
            const int* __restrict__ d_nids, const int* __restrict__ d_eids,
            const float* __restrict__ d_ts,
            const float* __restrict__ W_feat, const float* __restrict__ b_feat,
            const float* __restrict__ W_edge, const float* __restrict__ b_edge,
            const float* __restrict__ W_time, const float* __restrict__ b_time,
            const float* __restrict__ W_str,  const float* __restrict__ b_str,
            const float* __restrict__ W_out,  const float* __restrict__ b_out,
            const float* __restrict__ time_w, const float* __restrict__ time_b,
            const float* __restrict__ sWih, const float* __restrict__ sWhh,
            const float* __restrict__ sbih, const float* __restrict__ sbhh,
            const float* __restrict__ dWih, const float* __restrict__ dWhh,
            const float* __restrict__ dbih, const float* __restrict__ dbhh,
            float* __restrict__ out)
{
    __shared__ __align__(16) _Float16 xls[2][16 * 72];   // producer-PRIVATE x^T slots
    __shared__ __align__(16) _Float16 hls[2][16 * 72];   // h^T double buffer (hls[1] reused for e)
    __shared__ floatx4 gbuf[2][3][4][64];                // gi_r/gi_z/ia (+tail tacc) C-frags, 24 KB

    const int tid = threadIdx.x, w = tid >> 6, lane = tid & 63;
    const int g = lane >> 4, i16 = lane & 15;
    const bool is_src = (blockIdx.x & 1) == 0;
    const int b = (int)(blockIdx.x >> 1) * 16 + i16;     // this lane's item
    const int rw = (w + (int)blockIdx.x) & 3;            // role rotation (SIMD mixing)
    const int cp = (rw < 2) ? rw : (rw - 2);             // tile-pair: tiles {2cp, 2cp+1}

    const float SRZ = -1.44269504089f;   // -log2(e): sigmoid(x)=rcp(1+exp2(SRZ*x))
    const float SN  =  2.88539008178f;   // 2*log2(e): tanh(x)=1-2*rcp(exp2(SN*x)+1)
    const floatx4 z4 = {0, 0, 0, 0};

    // zero hls[0] (h(0) = 0)
    for (int q = tid; q < 16 * 72 / 2; q += 256) ((uint32_t*)hls[0])[q] = 0u;

    if (rw >= 2) {
        // ================= PRODUCER =================
        _Float16* xp = xls[cp];

        // full W_feat^T / bundle A-frags (all 4 tiles; needed for full-x build)
        uint4 wf[4][2];
        #pragma unroll
        for (int mt = 0; mt < 4; ++mt)
            #pragma unroll
            for (int kh = 0; kh < 2; ++kh) {
                float v[8];
                #pragma unroll
                for (int j = 0; j < 8; ++j)
                    v[j] = W_feat[(32 * kh + 8 * g + j) * 64 + 16 * mt + i16];
                wf[mt][kh] = make_uint4(pk2u(v[0],v[1]), pk2u(v[2],v[3]), pk2u(v[4],v[5]), pk2u(v[6],v[7]));
            }
        uint4 wtA[4];
        #pragma unroll
        for (int mt = 0; mt < 4; ++mt) {
            float v[8];
            #pragma unroll
            for (int j = 0; j < 8; ++j) {
                int k = 8 * g + j, dim = 16 * mt + i16;
                float x = 0.0f;
                if (k < 16)       x = W_time[k * 64 + dim];
                else if (k == 16) x = W_edge[dim];
                else if (k == 17) x = W_str[dim];
                else if (k == 18) x = b_edge[dim] + b_time[dim];
                else if (k == 19) x = is_src ? (b_feat[dim] + 2.0f * b_str[dim]) : b_str[dim];
                else if (k == 20) x = b_feat[dim];
                v[j] = x;
            }
            wtA[mt] = make_uint4(pk2u(v[0],v[1]), pk2u(v[2],v[3]), pk2u(v[4],v[5]), pk2u(v[6],v[7]));
        }
        // scaled Wih A-frags for OUR consumer's tiles only
        const float* WI = is_src ? sWih : dWih;
        uint4 wih[3][2][2];
        #pragma unroll
        for (int gt = 0; gt < 3; ++gt) {
            const float s = (gt == 2) ? SN : SRZ;
            #pragma unroll
            for (int tq = 0; tq < 2; ++tq)
                #pragma unroll
                for (int kh = 0; kh < 2; ++kh) {
                    int row = 64 * gt + 16 * (2 * cp + tq) + i16;
                    const float* p = WI + (size_t)row * 64 + 32 * kh + 8 * g;
                    float4 a = *(const float4*)p, c = *(const float4*)(p + 4);
                    wih[gt][tq][kh] = make_uint4(pk2u(s*a.x,s*a.y), pk2u(s*a.z,s*a.w),
                                                 pk2u(s*c.x,s*c.y), pk2u(s*c.z,s*c.w));
                }
        }
        float twc[8], tbc[8];
        #pragma unroll
        for (int j = 0; j < 8; ++j) {
            int k = 8 * (g & 1) + j;
            twc[j] = time_w[k]; tbc[j] = time_b[k];
        }

        const int* pn = (is_src ? s_nids : d_nids) + (size_t)b * NN;
        const int* pe = (is_src ? s_eids : d_eids) + (size_t)b * NN;
        const float* pt = (is_src ? s_ts : d_ts) + (size_t)b * NN;
        const float tqL = times[b];
        const int didL = dst_ids[b];
        const int oid = is_src ? didL : src_ids[b];
        const float dskill = is_src ? nodef[(size_t)didL * 64] : 0.0f;
        const float e00 = edgef[0];

        int nidC = pn[0], eidC = pe[0];
        float tsC = pt[0];
        float e0C = edgef[4 * (size_t)eidC];
        float4 nfa = {0,0,0,0}, nfb = {0,0,0,0}, nfc = {0,0,0,0}, nfd = {0,0,0,0};
        if (is_src) {
            const float* rp = nodef + (size_t)nidC * 64 + 8 * g;
            nfa = *(const float4*)rp;        nfb = *(const float4*)(rp + 4);
            nfc = *(const float4*)(rp + 32); nfd = *(const float4*)(rp + 36);
        }

        // build full x + gi for one step; x transposed through PRIVATE slot (no barrier)
        auto build_step = [&](int par) {
            float nsk = __shfl(nfa.x, i16);
            float sf = ((nidC == oid) ? 1.0f : 0.0f) +
                       ((is_src && nsk == dskill) ? 1.0f : 0.0f);
            float delta = tqL - tsC;
            uint4 tb4;
            if (g < 2) {
                float cv[8];
                #pragma unroll
                for (int j = 0; j < 8; ++j) cv[j] = __cosf(delta * twc[j] + tbc[j]);
                tb4 = make_uint4(pk2u(cv[0],cv[1]), pk2u(cv[2],cv[3]), pk2u(cv[4],cv[5]), pk2u(cv[6],cv[7]));
            } else if (g == 2) {
                tb4 = make_uint4(pk2u(e0C, sf), pk2u(1.0f, 1.0f), 0u, 0u);
            } else {
                tb4 = make_uint4(0u, 0u, 0u, 0u);
            }
            half8 tB = u2h(tb4);
            if (is_src) {
                uint4 nf0 = make_uint4(pk2u(nfa.x,nfa.y), pk2u(nfa.z,nfa.w), pk2u(nfb.x,nfb.y), pk2u(nfb.z,nfb.w));
                uint4 nf1 = make_uint4(pk2u(nfc.x,nfc.y), pk2u(nfc.z,nfc.w), pk2u(nfd.x,nfd.y), pk2u(nfd.z,nfd.w));
                half8 nB0 = u2h(nf0), nB1 = u2h(nf1);
                #pragma unroll
                for (int mt = 0; mt < 4; ++mt) {
                    floatx4 a = MFMA(u2h(wf[mt][0]), nB0, z4);
                    a = MFMA(u2h(wf[mt][1]), nB1, a);
                    floatx4 x = MFMA(u2h(wtA[mt]), tB, a);
                    *(uint2*)&xp[i16 * 72 + 16 * mt + 4 * g] =
                        make_uint2(pk2u(x[0], x[1]), pk2u(x[2], x[3]));
                }
            } else {
                #pragma unroll
                for (int mt = 0; mt < 4; ++mt) {
                    floatx4 x = MFMA(u2h(wtA[mt]), tB, z4);
                    *(uint2*)&xp[i16 * 72 + 16 * mt + 4 * g] =
                        make_uint2(pk2u(x[0], x[1]), pk2u(x[2], x[3]));
                }
            }
            half8 xB0 = u2h(*(const uint4*)&xp[i16 * 72 + 8 * g]);
            half8 xB1 = u2h(*(const uint4*)&xp[i16 * 72 + 32 + 8 * g]);
            #pragma unroll
            for (int gt = 0; gt < 3; ++gt)
                #pragma unroll
                for (int tq = 0; tq < 2; ++tq) {
                    floatx4 a = MFMA(u2h(wih[gt][tq][0]), xB0, z4);
                    gbuf[par][gt][2 * cp + tq][lane] = MFMA(u2h(wih[gt][tq][1]), xB1, a);
                }
        };

        // prologue: gi(0) -> gbuf[0]; load scalars(1); issue gathers(1)
        build_step(0);
        int nidN = pn[1], eidN = pe[1];
        float tsN = pt[1];
        float e0N = edgef[4 * (size_t)eidN];
        if (is_src) {
            const float* rp = nodef + (size_t)nidN * 64 + 8 * g;
            nfa = *(const float4*)rp;        nfb = *(const float4*)(rp + 4);
            nfc = *(const float4*)(rp + 32); nfd = *(const float4*)(rp + 36);
        }
        nidC = nidN; eidC = eidN; tsC = tsN; e0C = e0N;
        __syncthreads();

        for (int t = 0; t < NN; ++t) {
            if (t + 2 < NN) { nidN = pn[t + 2]; eidN = pe[t + 2]; tsN = pt[t + 2]; }
            if (t + 1 < NN) {
                build_step((t + 1) & 1);          // gi(t+1) -> gbuf[(t+1)&1]
            } else {
                // tail tacc -> gbuf[0][0][*] (C-layout; no transpose needed)
                uint4 tt4;
                if (g < 2) {
                    float cv[8];
                    #pragma unroll
                    for (int j = 0; j < 8; ++j) cv[j] = __cosf(tbc[j]);
                    tt4 = make_uint4(pk2u(cv[0],cv[1]), pk2u(cv[2],cv[3]), pk2u(cv[4],cv[5]), pk2u(cv[6],cv[7]));
                } else if (g == 2) {
                    tt4 = make_uint4(pk2u(e00, 0.0f), pk2u(1.0f, 0.0f), pk2u(is_src ? 0.0f : 1.0f, 0.0f), 0u);
                } else {
                    tt4 = make_uint4(0u, 0u, 0u, 0u);
                }
                half8 tT = u2h(tt4);
                #pragma unroll
                for (int tq = 0; tq < 2; ++tq) {
                    floatx4 tacc = MFMA(u2h(wtA[2 * cp + tq]), tT, z4);
                    if (!is_src) {   // nf regs hold nodef[didL] (prefetched at t==NN-2)
                        uint4 d0 = make_uint4(pk2u(nfa.x,nfa.y), pk2u(nfa.z,nfa.w), pk2u(nfb.x,nfb.y), pk2u(nfb.z,nfb.w));
                        uint4 d1 = make_uint4(pk2u(nfc.x,nfc.y), pk2u(nfc.z,nfc.w), pk2u(nfd.x,nfd.y), pk2u(nfd.z,nfd.w));
                        tacc = MFMA(u2h(wf[2 * cp + tq][0]), u2h(d0), tacc);
                        tacc = MFMA(u2h(wf[2 * cp + tq][1]), u2h(d1), tacc);
                    }
                    gbuf[0][0][2 * cp + tq][lane] = tacc;
                }
            }
            // issue gathers for (t+2); stay in flight across the barrier
            if (t + 2 < NN) {
                e0N = edgef[4 * (size_t)eidN];
                if (is_src) {
                    const float* rp = nodef + (size_t)nidN * 64 + 8 * g;
                    nfa = *(const float4*)rp;        nfb = *(const float4*)(rp + 4);
                    nfc = *(const float4*)(rp + 32); nfd = *(const float4*)(rp + 36);
                }
            } else if (t + 2 == NN && !is_src) {
                const float* rp = nodef + (size_t)didL * 64 + 8 * g;   // d-row for tail
                nfa = *(const float4*)rp;        nfb = *(const float4*)(rp + 4);
                nfc = *(const float4*)(rp + 32); nfd = *(const float4*)(rp + 36);
            }
            nidC = nidN; eidC = eidN; tsC = tsN; e0C = e0N;
            bar_lds();
        }
        bar_lds();   // epilogue bar (consumers exchange e)
    } else {
        // ================= CONSUMER =================
        const float* WH = is_src ? sWhh : dWhh;
        uint4 whh[3][2][2];
        #pragma unroll
        for (int gt = 0; gt < 3; ++gt) {
            const float s = (gt == 2) ? SN : SRZ;
            #pragma unroll
            for (int tq = 0; tq < 2; ++tq)
                #pragma unroll
                for (int kh = 0; kh < 2; ++kh) {
                    int row = 64 * gt + 16 * (2 * cp + tq) + i16;
                    const float* p = WH + (size_t)row * 64 + 32 * kh + 8 * g;
                    float4 a = *(const float4*)p, c = *(const float4*)(p + 4);
                    whh[gt][tq][kh] = make_uint4(pk2u(s*a.x,s*a.y), pk2u(s*a.z,s*a.w),
                                                 pk2u(s*c.x,s*c.y), pk2u(s*c.z,s*c.w));
                }
        }
        const float* BI = is_src ? sbih : dbih;
        const float* BH = is_src ? sbhh : dbhh;
        floatx4 brzr[2], brzz[2], binv[2], bhnv[2];
        #pragma unroll
        for (int tq = 0; tq < 2; ++tq) {
            int r0 = 16 * (2 * cp + tq) + 4 * g;
            #pragma unroll
            for (int r = 0; r < 4; ++r) {
                brzr[tq][r] = SRZ * (BI[r0 + r] + BH[r0 + r]);
                brzz[tq][r] = SRZ * (BI[64 + r0 + r] + BH[64 + r0 + r]);
                binv[tq][r] = SN * BI[128 + r0 + r];
                bhnv[tq][r] = SN * BH[128 + r0 + r];
            }
        }
        floatx4 hM[2] = {z4, z4};
        __syncthreads();

        for (int t = 0; t < NN; ++t) {
            const int par = t & 1;
            half8 hB0 = u2h(*(const uint4*)&hls[par][i16 * 72 + 8 * g]);
            half8 hB1 = u2h(*(const uint4*)&hls[par][i16 * 72 + 32 + 8 * g]);
            #pragma unroll
            for (int tq = 0; tq < 2; ++tq) {
                floatx4 cr = gbuf[par][0][2 * cp + tq][lane] + brzr[tq];
                floatx4 cz = gbuf[par][1][2 * cp + tq][lane] + brzz[tq];
                floatx4 iv = gbuf[par][2][2 * cp + tq][lane] + binv[tq];
                floatx4 a = MFMA(u2h(whh[0][tq][0]), hB0, cr);
                floatx4 rg = MFMA(u2h(whh[0][tq][1]), hB1, a);
                floatx4 c = MFMA(u2h(whh[1][tq][0]), hB0, cz);
                floatx4 zg = MFMA(u2h(whh[1][tq][1]), hB1, c);
                floatx4 e = MFMA(u2h(whh[2][tq][0]), hB0, bhnv[tq]);
                floatx4 ha = MFMA(u2h(whh[2][tq][1]), hB1, e);
                #pragma unroll
                for (int r = 0; r < 4; ++r) {
                    float rr = frcp(1.0f + fexp2(rg[r]));
                    float zz = frcp(1.0f + fexp2(zg[r]));
                    float vv = iv[r] + rr * ha[r];
                    float nn = 1.0f - 2.0f * frcp(fexp2(vv) + 1.0f);
                    hM[tq][r] = nn + zz * (hM[tq][r] - nn);
                }
                *(uint2*)&hls[par ^ 1][i16 * 72 + 32 * cp + 16 * tq + 4 * g] =
                    make_uint2(pk2u(hM[tq][0], hM[tq][1]), pk2u(hM[tq][2], hM[tq][3]));
            }
            bar_lds();
        }

        // epilogue: e = h(NN) + tacc; exchange via hls[1] (dead after final step)
        #pragma unroll
        for (int tq = 0; tq < 2; ++tq) {
            floatx4 e = hM[tq] + gbuf[0][0][2 * cp + tq][lane];
            *(uint2*)&hls[1][i16 * 72 + 32 * cp + 16 * tq + 4 * g] =
                make_uint2(pk2u(e[0], e[1]), pk2u(e[2], e[3]));
        }
        bar_lds();
        half8 eB0 = u2h(*(const uint4*)&hls[1][i16 * 72 + 8 * g]);
        half8 eB1 = u2h(*(const uint4*)&hls[1][i16 * 72 + 32 + 8 * g]);

        uint4 wo[2][2];
        #pragma unroll
        for (int tq = 0; tq < 2; ++tq)
            #pragma unroll
            for (int kh = 0; kh < 2; ++kh) {
                float v[8];
                #pragma unroll
                for (int j = 0; j < 8; ++j)
                    v[j] = W_out[(32 * kh + 8 * g + j) * 64 + 16 * (2 * cp + tq) + i16];
                wo[tq][kh] = make_uint4(pk2u(v[0],v[1]), pk2u(v[2],v[3]), pk2u(v[4],v[5]), pk2u(v[6],v[7]));
            }
        const size_t obase = (is_src ? 0 : (size_t)BB * 64) + (size_t)b * 64;
        #pragma unroll
        for (int tq = 0; tq < 2; ++tq) {
            floatx4 bo;
            #pragma unroll
            for (int r = 0; r < 4; ++r) bo[r] = b_out[16 * (2 * cp + tq) + 4 * g + r];
            floatx4 o = MFMA(u2h(wo[tq][0]), eB0, bo);
            o = MFMA(u2h(wo[tq][1]), eB1, o);
            *(floatx4*)(out + obase + 16 * (2 * cp + tq) + 4 * g) = o;
        }
    }
}

extern "C" void kernel_launch(void* const* d_in, const int* in_sizes, int n_in,
                              void* d_out, int out_size, void* d_ws, size_t ws_size,
                              hipStream_t stream) {
    (void)in_sizes; (void)n_in; (void)d_ws; (void)ws_size; (void)out_size;
    const float* nodef  = (const float*)d_in[0];
    const float* edgef  = (const float*)d_in[1];
    const int*   srcid  = (const int*)  d_in[2];
    const int*   dstid  = (const int*)  d_in[3];
    const float* times  = (const float*)d_in[4];
    const int*   s_nids = (const int*)  d_in[5];
    const int*   s_eids = (const int*)  d_in[6];
    const float* s_ts   = (const float*)d_in[7];
    const int*   d_nids = (const int*)  d_in[8];
    const int*   d_eids = (const int*)  d_in[9];
    const float* d_ts   = (const float*)d_in[10];
    const float* W_feat = (const float*)d_in[11];
    const float* b_feat = (const float*)d_in[12];
    const float* W_edge = (const float*)d_in[13];
    const float* b_edge = (const float*)d_in[14];
    const float* W_time = (const float*)d_in[15];
    const float* b_time = (const float*)d_in[16];
    const float* W_str  = (const float*)d_in[17];
    const float* b_str  = (const float*)d_in[18];
    const float* W_out  = (const float*)d_in[19];
    const float* b_out  = (const float*)d_in[20];
    const float* time_w = (const float*)d_in[21];
    const float* time_b = (const float*)d_in[22];
    const float* sWih   = (const float*)d_in[23];
    const float* sWhh   = (const float*)d_in[24];
    const float* sbih   = (const float*)d_in[25];
    const float* sbhh   = (const float*)d_in[26];
    const float* dWih   = (const float*)d_in[27];
    const float* dWhh   = (const float*)d_in[28];
    const float* dbih   = (const float*)d_in[29];
    const float* dbhh   = (const float*)d_in[30];

    dim3 grid(1024), block(256);
    dygkt8<<<grid, block, 0, stream>>>(
        nodef, edgef, srcid, dstid, times,
        s_nids, s_eids, s_ts, d_nids, d_eids, d_ts,
        W_feat, b_feat, W_edge, b_edge, W_time, b_time,
        W_str, b_str, W_out, b_out, time_w, time_b,
        sWih, sWhh, sbih, sbhh, dWih, dWhh, dbih, dbhh,
        (float*)d_out);
}